// Round 9
// baseline (406.910 us; speedup 1.0000x reference)
//
#include <hip/hip_runtime.h>
#include <hip/hip_cooperative_groups.h>
#include <math.h>

namespace cg = cooperative_groups;

// Problem constants (GNNObservationEncoder: 2-layer GAT, full graph)
#define Bc   8
#define Nc   1024
#define OBSc 64
#define HIDc 192
#define NHc  3
#define Dc   64
#define ALPHAc 0.2f
#define UNITS 768          // 24 bh x 32 row-chunks
#define AUXU  32           // adj-pack units

typedef __attribute__((ext_vector_type(8))) _Float16 half8;
typedef __attribute__((ext_vector_type(4))) float floatx4;

// Shared-memory arena, reused across phases
struct SM {
    union {
        _Float16 Bs[64][72];                                   // proj1 W-tile
        _Float16 Ts[64][40];                                   // transpose staging
        struct { float red[4][64][20]; float zs[4][16]; } ag;  // aggr reduce
    } u;
    float spsAi[32], spsAj[32], spsBi[32], spsBj[32];
};

// WhT swizzled (MFMA B-fragment order):
//   idx(bh, jt, c, lane, t) = (((bh*32 + jt)*4 + c)*64 + lane)*8 + t
//   element = Wh[j = jt*32 + (lane>>4)*8 + t][d = c*16 + (lane&15)]

// ---------------------------------------------------------------------------
__device__ void proj1_block(int unit, int tid, SM* sm,
    const float* __restrict__ xin, const float* __restrict__ W1,
    const float* __restrict__ a1, _Float16* __restrict__ WhT,
    float* __restrict__ si, float* __restrict__ sj, float* __restrict__ Mpart)
{
    const int bh = unit >> 5, chunk = unit & 31;
    const int b = bh / NHc, hh = bh % NHc;
    const int row0 = chunk * 32;

    for (int e = tid; e < OBSc * 64; e += 256) {
        int k = e >> 6, d = e & 63;
        sm->u.Bs[d][k] = (_Float16)W1[(size_t)hh * OBSc * 64 + e];
    }
    __syncthreads();

    const int lane = tid & 63, wv = tid >> 6;
    const int mblk = (wv & 1) * 16, nhalf = (wv >> 1) * 32;
    const int fr = lane & 15, fq = lane >> 4;
    floatx4 acc0 = {0.f,0.f,0.f,0.f}, acc1 = {0.f,0.f,0.f,0.f};
    const int row = row0 + mblk + fr;

#pragma unroll
    for (int ks = 0; ks < OBSc / 32; ++ks) {
        const int k0 = ks * 32 + fq * 8;
        const float* xr = xin + ((size_t)b * Nc + row) * OBSc + k0;
        float4 u0 = *(const float4*)xr;
        float4 u1 = *(const float4*)(xr + 4);
        half8 af;
        af[0] = (_Float16)u0.x; af[1] = (_Float16)u0.y;
        af[2] = (_Float16)u0.z; af[3] = (_Float16)u0.w;
        af[4] = (_Float16)u1.x; af[5] = (_Float16)u1.y;
        af[6] = (_Float16)u1.z; af[7] = (_Float16)u1.w;
        half8 b0 = *(const half8*)&sm->u.Bs[nhalf + fr][k0];
        half8 b1 = *(const half8*)&sm->u.Bs[nhalf + 16 + fr][k0];
        acc0 = __builtin_amdgcn_mfma_f32_16x16x32_f16(af, b0, acc0, 0, 0, 0);
        acc1 = __builtin_amdgcn_mfma_f32_16x16x32_f16(af, b1, acc1, 0, 0, 0);
    }

    // fused s_i / s_j
    const float al0 = a1[hh * 2 * Dc + nhalf + fr];
    const float al1 = a1[hh * 2 * Dc + nhalf + 16 + fr];
    const float ar0 = a1[hh * 2 * Dc + Dc + nhalf + fr];
    const float ar1 = a1[hh * 2 * Dc + Dc + nhalf + 16 + fr];
    float pi[4], pj[4];
#pragma unroll
    for (int r = 0; r < 4; ++r) {
        pi[r] = acc0[r] * al0 + acc1[r] * al1;
        pj[r] = acc0[r] * ar0 + acc1[r] * ar1;
        for (int off = 8; off >= 1; off >>= 1) {
            pi[r] += __shfl_xor(pi[r], off, 64);
            pj[r] += __shfl_xor(pj[r], off, 64);
        }
    }
    if (fr == 0) {
#pragma unroll
        for (int r = 0; r < 4; ++r) {
            int lr = mblk + fq * 4 + r;
            if (nhalf == 0) { sm->spsAi[lr] = pi[r]; sm->spsAj[lr] = pj[r]; }
            else            { sm->spsBi[lr] = pi[r]; sm->spsBj[lr] = pj[r]; }
        }
    }
    __syncthreads();
    if (tid < 64) {
        float vj = -INFINITY;
        if (tid < 32) {
            size_t g = (size_t)bh * Nc + row0 + tid;
            si[g] = sm->spsAi[tid] + sm->spsBi[tid];
            vj    = sm->spsAj[tid] + sm->spsBj[tid];
            sj[g] = vj;
        }
        float mv = vj;
        for (int off = 32; off >= 1; off >>= 1) mv = fmaxf(mv, __shfl_xor(mv, off, 64));
        if (tid == 0) Mpart[bh * 32 + chunk] = mv;   // per-chunk sj max
    }

    // Wh -> Ts -> swizzled WhT
#pragma unroll
    for (int nt = 0; nt < 2; ++nt) {
        const int d = nhalf + nt * 16 + fr;
        floatx4 acc = nt ? acc1 : acc0;
#pragma unroll
        for (int p = 0; p < 2; ++p) {
            union { unsigned int w; _Float16 h[2]; } pk;
            pk.h[0] = (_Float16)acc[2 * p];
            pk.h[1] = (_Float16)acc[2 * p + 1];
            *(unsigned int*)&sm->u.Ts[d][mblk + fq * 4 + 2 * p] = pk.w;
        }
    }
    __syncthreads();
    {
        const int c2 = tid >> 6, lane2 = tid & 63;
        const int fr2 = lane2 & 15, fq2 = lane2 >> 4;
        uint4 v = *(const uint4*)&sm->u.Ts[c2 * 16 + fr2][fq2 * 8];
        *(uint4*)&WhT[(size_t)(bh * 32 + chunk) * 2048 + tid * 8] = v;
    }
    __syncthreads();   // sm safe for next unit/phase
}

// ---------------------------------------------------------------------------
// aux unit: adj bit-pack (all 32) + W2 -> swizzled fp16 (first 12)
// ---------------------------------------------------------------------------
__device__ void aux_block(int px, int tid,
    const float* __restrict__ adj, unsigned long long* __restrict__ adjb,
    const float* __restrict__ W2, _Float16* __restrict__ W2T)
{
    const int wv = tid >> 6, lane = tid & 63;
    for (int r8 = 0; r8 < 8; ++r8) {
        const int i = px * 32 + wv * 8 + r8;
        unsigned long long word = 0;
        for (int g = 0; g < 16; ++g) {
            bool c = adj[(size_t)i * Nc + g * 64 + lane] > 0.f;
            unsigned long long bal = __ballot(c);
            if (lane == g) word = bal;
        }
        if (lane < 16) adjb[(size_t)i * 16 + lane] = word;
    }
    if (px < 12) {
        for (int e = px * 3072 + tid; e < px * 3072 + 3072; e += 256) {
            int t = e & 7, ln = (e >> 3) & 63, p = (e >> 9) & 1, nh = (e >> 10) & 1;
            int gg = e >> 11; int ks = gg % 6, hh = gg / 6;
            int k = ks * 32 + (ln >> 4) * 8 + t;
            int d = nh * 32 + p * 16 + (ln & 15);
            W2T[e] = (_Float16)W2[((size_t)hh * HIDc + k) * Dc + d];
        }
    }
}

// ---------------------------------------------------------------------------
__device__ void proj2_block(int unit, int tid, SM* sm,
    const _Float16* __restrict__ xh, const _Float16* __restrict__ W2T,
    const float* __restrict__ a2, _Float16* __restrict__ WhT,
    float* __restrict__ si, float* __restrict__ sj, float* __restrict__ Mpart)
{
    const int bh = unit >> 5, chunk = unit & 31;
    const int b = bh / NHc, hh = bh % NHc;
    const int row0 = chunk * 32;
    const int lane = tid & 63, wv = tid >> 6;
    const int mblk = (wv & 1) * 16, nhalf = (wv >> 1) * 32;
    const int fr = lane & 15, fq = lane >> 4;
    const int nh = nhalf >> 5;

    floatx4 acc0 = {0.f,0.f,0.f,0.f}, acc1 = {0.f,0.f,0.f,0.f};
    const int row = row0 + mblk + fr;

#pragma unroll
    for (int ks = 0; ks < HIDc / 32; ++ks) {
        half8 af = *(const half8*)&xh[((size_t)b * Nc + row) * HIDc + ks * 32 + fq * 8];
        const _Float16* wb = W2T + (size_t)((hh * 6 + ks) * 2 + nh) * 1024 + lane * 8;
        half8 b0 = *(const half8*)wb;
        half8 b1 = *(const half8*)(wb + 512);
        acc0 = __builtin_amdgcn_mfma_f32_16x16x32_f16(af, b0, acc0, 0, 0, 0);
        acc1 = __builtin_amdgcn_mfma_f32_16x16x32_f16(af, b1, acc1, 0, 0, 0);
    }

    const float al0 = a2[hh * 2 * Dc + nhalf + fr];
    const float al1 = a2[hh * 2 * Dc + nhalf + 16 + fr];
    const float ar0 = a2[hh * 2 * Dc + Dc + nhalf + fr];
    const float ar1 = a2[hh * 2 * Dc + Dc + nhalf + 16 + fr];
    float pi[4], pj[4];
#pragma unroll
    for (int r = 0; r < 4; ++r) {
        pi[r] = acc0[r] * al0 + acc1[r] * al1;
        pj[r] = acc0[r] * ar0 + acc1[r] * ar1;
        for (int off = 8; off >= 1; off >>= 1) {
            pi[r] += __shfl_xor(pi[r], off, 64);
            pj[r] += __shfl_xor(pj[r], off, 64);
        }
    }
    if (fr == 0) {
#pragma unroll
        for (int r = 0; r < 4; ++r) {
            int lr = mblk + fq * 4 + r;
            if (nhalf == 0) { sm->spsAi[lr] = pi[r]; sm->spsAj[lr] = pj[r]; }
            else            { sm->spsBi[lr] = pi[r]; sm->spsBj[lr] = pj[r]; }
        }
    }
    __syncthreads();
    if (tid < 64) {
        float vj = -INFINITY;
        if (tid < 32) {
            size_t g = (size_t)bh * Nc + row0 + tid;
            si[g] = sm->spsAi[tid] + sm->spsBi[tid];
            vj    = sm->spsAj[tid] + sm->spsBj[tid];
            sj[g] = vj;
        }
        float mv = vj;
        for (int off = 32; off >= 1; off >>= 1) mv = fmaxf(mv, __shfl_xor(mv, off, 64));
        if (tid == 0) Mpart[bh * 32 + chunk] = mv;
    }

#pragma unroll
    for (int nt = 0; nt < 2; ++nt) {
        const int d = nhalf + nt * 16 + fr;
        floatx4 acc = nt ? acc1 : acc0;
#pragma unroll
        for (int p = 0; p < 2; ++p) {
            union { unsigned int w; _Float16 h[2]; } pk;
            pk.h[0] = (_Float16)acc[2 * p];
            pk.h[1] = (_Float16)acc[2 * p + 1];
            *(unsigned int*)&sm->u.Ts[d][mblk + fq * 4 + 2 * p] = pk.w;
        }
    }
    __syncthreads();
    {
        const int c2 = tid >> 6, lane2 = tid & 63;
        const int fr2 = lane2 & 15, fq2 = lane2 >> 4;
        uint4 v = *(const uint4*)&sm->u.Ts[c2 * 16 + fr2][fq2 * 8];
        *(uint4*)&WhT[(size_t)(bh * 32 + chunk) * 2048 + tid * 8] = v;
    }
    __syncthreads();
}

// ---------------------------------------------------------------------------
// aggr unit: (bh, 32-row chunk). 4 waves: row-half g = wv>>1, K-half kh = wv&1.
// Per wave: 16 rows x 64 d x K=512, 16 pipelined iterations, no K-loop barrier.
// ---------------------------------------------------------------------------
template <bool DO_ELU, typename OutT>
__device__ void aggr_block(int unit, int tid, SM* sm,
    const _Float16* __restrict__ WhT, const float* __restrict__ si,
    const float* __restrict__ sj, const float* __restrict__ Mpart,
    const unsigned long long* __restrict__ adjb, OutT* __restrict__ outp)
{
    const int wv = tid >> 6, lane = tid & 63;
    const int bh = unit >> 5;
    const int row0 = (unit & 31) << 5;
    const int b = bh / NHc, hh = bh % NHc;
    const int fr = lane & 15, fq = lane >> 4;
    const int g  = wv >> 1;
    const int kh = wv & 1;
    const int row = row0 + g * 16 + fr;

    // M = max over the 32 per-chunk partials
    float mpv = Mpart[bh * 32 + (lane & 31)];
    for (int off = 16; off >= 1; off >>= 1) mpv = fmaxf(mpv, __shfl_xor(mpv, off, 64));

    const float s_i = si[(size_t)bh * Nc + row];
    const float em  = s_i + mpv;
    const float m_i = fmaxf(em, ALPHAc * em);  // = max_j leaky(s_i+s_j), full adj

    const float* sjr = sj + (size_t)bh * Nc;
    const unsigned long long* arow = adjb + (size_t)row * 16;
    const _Float16* Bp = WhT + (size_t)bh * 65536 + (size_t)kh * 32768 + lane * 8;

    floatx4 acc[4] = {{0.f,0.f,0.f,0.f},{0.f,0.f,0.f,0.f},
                      {0.f,0.f,0.f,0.f},{0.f,0.f,0.f,0.f}};
    float zacc = 0.f;

    float4 sa = *(const float4*)&sjr[(kh * 16) * 32 + fq * 8];
    float4 sb = *(const float4*)&sjr[(kh * 16) * 32 + fq * 8 + 4];
    unsigned long long w = arow[(kh * 16) >> 1];
    half8 bfr0 = *(const half8*)(Bp);
    half8 bfr1 = *(const half8*)(Bp + 512);
    half8 bfr2 = *(const half8*)(Bp + 1024);
    half8 bfr3 = *(const half8*)(Bp + 1536);

#pragma unroll
    for (int s16 = 0; s16 < 16; ++s16) {
        const int s = kh * 16 + s16;
        float4 nsa, nsb; unsigned long long nw;
        half8 nb0, nb1, nb2, nb3;
        if (s16 < 15) {
            const int jn = (s + 1) * 32 + fq * 8;
            nsa = *(const float4*)&sjr[jn];
            nsb = *(const float4*)&sjr[jn + 4];
            nw  = arow[(s + 1) >> 1];
            const _Float16* bn = Bp + (size_t)(s16 + 1) * 2048;
            nb0 = *(const half8*)(bn);
            nb1 = *(const half8*)(bn + 512);
            nb2 = *(const half8*)(bn + 1024);
            nb3 = *(const half8*)(bn + 1536);
        }
        const int bb = (s & 1) * 32 + fq * 8;
        const float sv[8] = {sa.x, sa.y, sa.z, sa.w, sb.x, sb.y, sb.z, sb.w};
        float p[8];
        if (w == ~0ULL) {
#pragma unroll
            for (int t = 0; t < 8; ++t) {
                float e = s_i + sv[t];
                e = fmaxf(e, ALPHAc * e) - m_i;
                p[t] = __expf(e);
            }
        } else {
#pragma unroll
            for (int t = 0; t < 8; ++t) {
                float e = s_i + sv[t];
                e = fmaxf(e, ALPHAc * e) - m_i;
                e = ((w >> (bb + t)) & 1) ? e : -1e30f;
                p[t] = __expf(e);
            }
        }
        zacc += ((p[0] + p[1]) + (p[2] + p[3])) + ((p[4] + p[5]) + (p[6] + p[7]));
        union { half8 v; _Float16 h[8]; } A;
#pragma unroll
        for (int t = 0; t < 8; ++t) A.h[t] = (_Float16)p[t];
        acc[0] = __builtin_amdgcn_mfma_f32_16x16x32_f16(A.v, bfr0, acc[0], 0, 0, 0);
        acc[1] = __builtin_amdgcn_mfma_f32_16x16x32_f16(A.v, bfr1, acc[1], 0, 0, 0);
        acc[2] = __builtin_amdgcn_mfma_f32_16x16x32_f16(A.v, bfr2, acc[2], 0, 0, 0);
        acc[3] = __builtin_amdgcn_mfma_f32_16x16x32_f16(A.v, bfr3, acc[3], 0, 0, 0);
        if (s16 < 15) {
            sa = nsa; sb = nsb; w = nw;
            bfr0 = nb0; bfr1 = nb1; bfr2 = nb2; bfr3 = nb3;
        }
    }

    zacc += __shfl_xor(zacc, 16, 64);
    zacc += __shfl_xor(zacc, 32, 64);
    if (lane < 16) sm->u.ag.zs[wv][lane] = zacc;
#pragma unroll
    for (int c = 0; c < 4; ++c)
        *(floatx4*)&sm->u.ag.red[wv][lane][c * 4] = acc[c];
    __syncthreads();

    // combine K-halves: waves {2g, 2g+1} share row-group g; wave kh takes c-pair
    const int w0 = g * 2;
#pragma unroll
    for (int cc = 0; cc < 2; ++cc) {
        const int c = kh * 2 + cc;
        floatx4 af;
#pragma unroll
        for (int reg = 0; reg < 4; ++reg)
            af[reg] = sm->u.ag.red[w0][lane][c * 4 + reg]
                    + sm->u.ag.red[w0 + 1][lane][c * 4 + reg];
#pragma unroll
        for (int reg = 0; reg < 4; ++reg) {
            const int r = fq * 4 + reg;
            const float Z = sm->u.ag.zs[w0][r] + sm->u.ag.zs[w0 + 1][r];
            float v = af[reg] / Z;
            if (DO_ELU) v = v > 0.f ? v : expm1f(v);
            outp[((size_t)b * Nc + row0 + g * 16 + r) * HIDc + hh * Dc + c * 16 + fr] = (OutT)v;
        }
    }
    __syncthreads();
}

// ---------------------------------------------------------------------------
// Cooperative mega-kernel: grid-stride phases + grid.sync between them.
// ---------------------------------------------------------------------------
__global__ __launch_bounds__(256, 3) void gat_mega(
    const float* __restrict__ xin, const float* __restrict__ adj,
    const float* __restrict__ W1, const float* __restrict__ a1,
    const float* __restrict__ W2, const float* __restrict__ a2,
    float* __restrict__ out,
    _Float16* __restrict__ WhT1, _Float16* __restrict__ WhT2,
    _Float16* __restrict__ xh, unsigned long long* __restrict__ adjb,
    _Float16* __restrict__ W2T,
    float* __restrict__ si1, float* __restrict__ sj1,
    float* __restrict__ si2, float* __restrict__ sj2,
    float* __restrict__ Mp1, float* __restrict__ Mp2)
{
    __shared__ SM sm;
    const int tid = threadIdx.x;
    cg::grid_group grid = cg::this_grid();

    for (int u = blockIdx.x; u < UNITS + AUXU; u += gridDim.x) {
        if (u < UNITS) proj1_block(u, tid, &sm, xin, W1, a1, WhT1, si1, sj1, Mp1);
        else           aux_block(u - UNITS, tid, adj, adjb, W2, W2T);
    }
    __threadfence(); grid.sync(); __threadfence();

    for (int u = blockIdx.x; u < UNITS; u += gridDim.x)
        aggr_block<true, _Float16>(u, tid, &sm, WhT1, si1, sj1, Mp1, adjb, xh);
    __threadfence(); grid.sync(); __threadfence();

    for (int u = blockIdx.x; u < UNITS; u += gridDim.x)
        proj2_block(u, tid, &sm, xh, W2T, a2, WhT2, si2, sj2, Mp2);
    __threadfence(); grid.sync(); __threadfence();

    for (int u = blockIdx.x; u < UNITS; u += gridDim.x)
        aggr_block<false, float>(u, tid, &sm, WhT2, si2, sj2, Mp2, adjb, out);
}

// ---------------------------------------------------------------------------
// Fallback wrappers (ordinary launches; kernel boundaries give coherence)
// ---------------------------------------------------------------------------
__global__ __launch_bounds__(256, 3) void k_phase1(
    const float* xin, const float* adj, const float* W1, const float* a1,
    const float* W2, _Float16* WhT1, _Float16* W2T,
    unsigned long long* adjb, float* si, float* sj, float* Mp)
{
    __shared__ SM sm;
    if (blockIdx.x < UNITS) proj1_block(blockIdx.x, threadIdx.x, &sm, xin, W1, a1, WhT1, si, sj, Mp);
    else                    aux_block(blockIdx.x - UNITS, threadIdx.x, adj, adjb, W2, W2T);
}
__global__ __launch_bounds__(256, 3) void k_aggr1(
    const _Float16* WhT, const float* si, const float* sj, const float* Mp,
    const unsigned long long* adjb, _Float16* xh)
{
    __shared__ SM sm;
    aggr_block<true, _Float16>(blockIdx.x, threadIdx.x, &sm, WhT, si, sj, Mp, adjb, xh);
}
__global__ __launch_bounds__(256, 3) void k_proj2(
    const _Float16* xh, const _Float16* W2T, const float* a2,
    _Float16* WhT2, float* si, float* sj, float* Mp)
{
    __shared__ SM sm;
    proj2_block(blockIdx.x, threadIdx.x, &sm, xh, W2T, a2, WhT2, si, sj, Mp);
}
__global__ __launch_bounds__(256, 3) void k_aggr2(
    const _Float16* WhT, const float* si, const float* sj, const float* Mp,
    const unsigned long long* adjb, float* out)
{
    __shared__ SM sm;
    aggr_block<false, float>(blockIdx.x, threadIdx.x, &sm, WhT, si, sj, Mp, adjb, out);
}

// ---------------------------------------------------------------------------
extern "C" void kernel_launch(void* const* d_in, const int* in_sizes, int n_in,
                              void* d_out, int out_size, void* d_ws, size_t ws_size,
                              hipStream_t stream) {
    const float* h_in = (const float*)d_in[0];   // (B,N,OBS)
    const float* adj  = (const float*)d_in[1];   // (N,N)
    const float* W1   = (const float*)d_in[2];   // (NH,OBS,D)
    const float* a1   = (const float*)d_in[3];   // (NH,2D)
    const float* W2   = (const float*)d_in[4];   // (NH,HID,D)
    const float* a2   = (const float*)d_in[5];   // (NH,2D)
    float* out = (float*)d_out;

    float* ws = (float*)d_ws;
    const size_t nWhT_f = (size_t)Bc * NHc * Dc * Nc / 2;   // 786432 floats each
    const size_t nXh_f  = (size_t)Bc * Nc * HIDc / 2;       // 786432
    const size_t nAb_f  = (size_t)Nc * 16 * 2;              // 32768
    const size_t nW2T_f = 36864 / 2;                        // 18432
    const size_t nR     = (size_t)Bc * NHc * Nc;            // 24576
    _Float16* WhT1 = (_Float16*)ws;
    _Float16* WhT2 = (_Float16*)(ws + nWhT_f);
    _Float16* xh   = (_Float16*)(ws + 2 * nWhT_f);
    unsigned long long* adjb = (unsigned long long*)(ws + 2 * nWhT_f + nXh_f);
    _Float16* W2T  = (_Float16*)(ws + 2 * nWhT_f + nXh_f + nAb_f);
    float* si1 = ws + 2 * nWhT_f + nXh_f + nAb_f + nW2T_f;
    float* sj1 = si1 + nR;
    float* si2 = sj1 + nR;
    float* sj2 = si2 + nR;
    float* Mp1 = sj2 + nR;       // 768 floats
    float* Mp2 = Mp1 + UNITS;    // 768 floats

    // Cooperative path: size grid from queried occupancy, grid-stride phases.
    int dev = 0, cus = 256, nb = 0;
    (void)hipGetDevice(&dev);
    (void)hipDeviceGetAttribute(&cus, hipDeviceAttributeMultiprocessorCount, dev);
    (void)hipOccupancyMaxActiveBlocksPerMultiprocessor(&nb, gat_mega, 256, 0);
    int grid = nb * cus;
    if (grid > UNITS + AUXU) grid = UNITS + AUXU;

    hipError_t err = hipErrorUnknown;
    if (grid >= 64) {
        void* kargs[] = {
            (void*)&h_in, (void*)&adj, (void*)&W1, (void*)&a1, (void*)&W2, (void*)&a2,
            (void*)&out, (void*)&WhT1, (void*)&WhT2, (void*)&xh, (void*)&adjb,
            (void*)&W2T, (void*)&si1, (void*)&sj1, (void*)&si2, (void*)&sj2,
            (void*)&Mp1, (void*)&Mp2
        };
        err = hipLaunchCooperativeKernel((void*)gat_mega, dim3(grid), dim3(256),
                                         kargs, 0, stream);
    }
    if (err != hipSuccess) {
        // Fallback: 4 ordinary launches (same device code, kernel-boundary coherence)
        k_phase1<<<UNITS + AUXU, 256, 0, stream>>>(h_in, adj, W1, a1, W2,
                                                   WhT1, W2T, adjb, si1, sj1, Mp1);
        k_aggr1<<<UNITS, 256, 0, stream>>>(WhT1, si1, sj1, Mp1, adjb, xh);
        k_proj2<<<UNITS, 256, 0, stream>>>(xh, W2T, a2, WhT2, si2, sj2, Mp2);
        k_aggr2<<<UNITS, 256, 0, stream>>>(WhT2, si2, sj2, Mp2, adjb, out);
    }
}

// Round 10
// 119.193 us; speedup vs baseline: 3.4139x; 3.4139x over previous
//
#include <hip/hip_runtime.h>
#include <math.h>

// Problem constants (GNNObservationEncoder: 2-layer GAT, full graph)
#define Bc   8
#define Nc   1024
#define OBSc 64
#define HIDc 192
#define NHc  3
#define Dc   64
#define ALPHAc 0.2f

typedef __attribute__((ext_vector_type(8))) _Float16 half8;
typedef __attribute__((ext_vector_type(4))) float floatx4;

// WhT swizzled (MFMA B-fragment order):
//   idx(bh, jt, c, lane, t) = (((bh*32 + jt)*4 + c)*64 + lane)*8 + t
//   element = Wh[j = jt*32 + (lane>>4)*8 + t][d = c*16 + (lane&15)]

// ---------------------------------------------------------------------------
// P1: proj1 (Wh1 = x @ W1, fp16 MFMA) + aux y-slice (adj bit-pack, W2->W2T).
// Grid (32, 25) x 256. Writes swizzled WhT1, si1/sj1, Mp1[bh*32+chunk].
// ---------------------------------------------------------------------------
__global__ __launch_bounds__(256) void k_proj1(
    const float* __restrict__ xin, const float* __restrict__ W1,
    const float* __restrict__ a1, _Float16* __restrict__ WhT,
    float* __restrict__ si, float* __restrict__ sj, float* __restrict__ Mp1,
    const float* __restrict__ adj, unsigned long long* __restrict__ adjb,
    const float* __restrict__ W2, _Float16* __restrict__ W2T)
{
    const int tid = threadIdx.x;
    const int bh  = blockIdx.y;

    if (bh == Bc * NHc) {
        const int px = blockIdx.x, wv = tid >> 6, lane = tid & 63;
        for (int r8 = 0; r8 < 8; ++r8) {
            const int i = px * 32 + wv * 8 + r8;
            unsigned long long word = 0;
            for (int g = 0; g < 16; ++g) {
                bool c = adj[(size_t)i * Nc + g * 64 + lane] > 0.f;
                unsigned long long bal = __ballot(c);
                if (lane == g) word = bal;
            }
            if (lane < 16) adjb[(size_t)i * 16 + lane] = word;
        }
        if (px < 12) {
            // W2 -> swizzled fp16: idx = (((hh*6+ks)*2+nh)*2+p)*512 + ln*8 + t
            for (int e = px * 3072 + tid; e < px * 3072 + 3072; e += 256) {
                int t = e & 7, ln = (e >> 3) & 63, p = (e >> 9) & 1, nh = (e >> 10) & 1;
                int g = e >> 11; int ks = g % 6, hh = g / 6;
                int k = ks * 32 + (ln >> 4) * 8 + t;
                int d = nh * 32 + p * 16 + (ln & 15);
                W2T[e] = (_Float16)W2[((size_t)hh * HIDc + k) * Dc + d];
            }
        }
        return;
    }

    __shared__ union {
        _Float16 Bs[64][OBSc + 8];
        _Float16 Ts[64][40];
    } u;
    __shared__ float spsAi[32], spsAj[32], spsBi[32], spsBj[32];

    const int b = bh / NHc, hh = bh % NHc;
    const int row0 = blockIdx.x * 32;

    for (int e = tid; e < OBSc * 64; e += 256) {
        int k = e >> 6, d = e & 63;
        u.Bs[d][k] = (_Float16)W1[(size_t)hh * OBSc * 64 + e];
    }
    __syncthreads();

    const int lane = tid & 63, wv = tid >> 6;
    const int mblk = (wv & 1) * 16, nhalf = (wv >> 1) * 32;
    const int fr = lane & 15, fq = lane >> 4;
    floatx4 acc0 = {0.f,0.f,0.f,0.f}, acc1 = {0.f,0.f,0.f,0.f};
    const int row = row0 + mblk + fr;

#pragma unroll
    for (int ks = 0; ks < OBSc / 32; ++ks) {
        const int k0 = ks * 32 + fq * 8;
        const float* xr = xin + ((size_t)b * Nc + row) * OBSc + k0;
        float4 u0 = *(const float4*)xr;
        float4 u1 = *(const float4*)(xr + 4);
        half8 af;
        af[0] = (_Float16)u0.x; af[1] = (_Float16)u0.y;
        af[2] = (_Float16)u0.z; af[3] = (_Float16)u0.w;
        af[4] = (_Float16)u1.x; af[5] = (_Float16)u1.y;
        af[6] = (_Float16)u1.z; af[7] = (_Float16)u1.w;
        half8 b0 = *(const half8*)&u.Bs[nhalf + fr][k0];
        half8 b1 = *(const half8*)&u.Bs[nhalf + 16 + fr][k0];
        acc0 = __builtin_amdgcn_mfma_f32_16x16x32_f16(af, b0, acc0, 0, 0, 0);
        acc1 = __builtin_amdgcn_mfma_f32_16x16x32_f16(af, b1, acc1, 0, 0, 0);
    }

    // fused s_i / s_j
    const float al0 = a1[hh * 2 * Dc + nhalf + fr];
    const float al1 = a1[hh * 2 * Dc + nhalf + 16 + fr];
    const float ar0 = a1[hh * 2 * Dc + Dc + nhalf + fr];
    const float ar1 = a1[hh * 2 * Dc + Dc + nhalf + 16 + fr];
    float pi[4], pj[4];
#pragma unroll
    for (int r = 0; r < 4; ++r) {
        pi[r] = acc0[r] * al0 + acc1[r] * al1;
        pj[r] = acc0[r] * ar0 + acc1[r] * ar1;
        for (int off = 8; off >= 1; off >>= 1) {
            pi[r] += __shfl_xor(pi[r], off, 64);
            pj[r] += __shfl_xor(pj[r], off, 64);
        }
    }
    if (fr == 0) {
#pragma unroll
        for (int r = 0; r < 4; ++r) {
            int lr = mblk + fq * 4 + r;
            if (nhalf == 0) { spsAi[lr] = pi[r]; spsAj[lr] = pj[r]; }
            else            { spsBi[lr] = pi[r]; spsBj[lr] = pj[r]; }
        }
    }
    __syncthreads();
    if (tid < 64) {
        float vj = -INFINITY;
        if (tid < 32) {
            size_t g = (size_t)bh * Nc + row0 + tid;
            si[g] = spsAi[tid] + spsBi[tid];
            vj    = spsAj[tid] + spsBj[tid];
            sj[g] = vj;
        }
        float mv = vj;
        for (int off = 32; off >= 1; off >>= 1) mv = fmaxf(mv, __shfl_xor(mv, off, 64));
        if (tid == 0) Mp1[bh * 32 + blockIdx.x] = mv;
    }

    // Wh -> Ts -> swizzled WhT
#pragma unroll
    for (int nt = 0; nt < 2; ++nt) {
        const int d = nhalf + nt * 16 + fr;
        floatx4 acc = nt ? acc1 : acc0;
#pragma unroll
        for (int p = 0; p < 2; ++p) {
            union { unsigned int w; _Float16 h[2]; } pk;
            pk.h[0] = (_Float16)acc[2 * p];
            pk.h[1] = (_Float16)acc[2 * p + 1];
            *(unsigned int*)&u.Ts[d][mblk + fq * 4 + 2 * p] = pk.w;
        }
    }
    __syncthreads();
    {
        const int c2 = tid >> 6, lane2 = tid & 63;
        const int fr2 = lane2 & 15, fq2 = lane2 >> 4;
        const int jt = row0 >> 5;
        uint4 v = *(const uint4*)&u.Ts[c2 * 16 + fr2][fq2 * 8];
        *(uint4*)&WhT[(size_t)(bh * 32 + jt) * 2048 + tid * 8] = v;
    }
}

// ---------------------------------------------------------------------------
// P2: aggr layer-1 + ELU + proj2 FUSED. Block = (b, 16-row chunk), 384 thr.
// Waves (hh = wv>>1, kh = wv&1): aggr 16 rows x 64 d, K-half kh (16 pipelined
// iters); LDS-combine; ELU -> fp16 xh tile in LDS (never to HBM); then proj2
// MFMA (K=192) from the LDS tile + W2T. Emits WhT2 (swizzled), si2/sj2, Mp2.
// Grid 512 x 384 = 3072 waves = 12 waves/CU (2 blocks/CU).
// ---------------------------------------------------------------------------
__global__ __launch_bounds__(384, 2) void k_fused(
    const _Float16* __restrict__ WhT1,
    const float* __restrict__ si1, const float* __restrict__ sj1,
    const float* __restrict__ Mp1, const unsigned long long* __restrict__ adjb,
    const _Float16* __restrict__ W2T, const float* __restrict__ a2,
    _Float16* __restrict__ WhT2,
    float* __restrict__ si2, float* __restrict__ sj2, float* __restrict__ Mp2)
{
    __shared__ union {
        struct { float red[6][64][20]; float zs[6][16]; } ag;  // ~31.1 KB
        _Float16 Ts3[3][64][24];                               // 9.2 KB (red dead)
    } uR;
    __shared__ _Float16 xhs[16][208];       // 6.7 KB (row stride 416 B = 26x16B)
    __shared__ float sp2i[6][16], sp2j[6][16];

    const int tid = threadIdx.x, wv = tid >> 6, lane = tid & 63;
    const int b = blockIdx.x >> 6, c16 = blockIdx.x & 63;
    const int row0 = c16 * 16;
    const int hh = wv >> 1, kh = wv & 1;
    const int bh = b * NHc + hh;
    const int fr = lane & 15, fq = lane >> 4;
    const int row = row0 + fr;

    // ---- aggr layer 1 (K-half kh) ----
    float mpv = Mp1[bh * 32 + (lane & 31)];
    for (int off = 16; off >= 1; off >>= 1) mpv = fmaxf(mpv, __shfl_xor(mpv, off, 64));
    const float s_i = si1[(size_t)bh * Nc + row];
    const float em  = s_i + mpv;
    const float m_i = fmaxf(em, ALPHAc * em);   // = max_j leaky(s_i+s_j), full adj

    const float* sjr = sj1 + (size_t)bh * Nc;
    const unsigned long long* arow = adjb + (size_t)row * 16;
    const _Float16* Bp = WhT1 + (size_t)bh * 65536 + (size_t)kh * 32768 + lane * 8;

    floatx4 acc[4] = {{0.f,0.f,0.f,0.f},{0.f,0.f,0.f,0.f},
                      {0.f,0.f,0.f,0.f},{0.f,0.f,0.f,0.f}};
    float zacc = 0.f;

    float4 sa = *(const float4*)&sjr[(kh * 16) * 32 + fq * 8];
    float4 sb = *(const float4*)&sjr[(kh * 16) * 32 + fq * 8 + 4];
    unsigned long long w = arow[(kh * 16) >> 1];
    half8 bfr0 = *(const half8*)(Bp);
    half8 bfr1 = *(const half8*)(Bp + 512);
    half8 bfr2 = *(const half8*)(Bp + 1024);
    half8 bfr3 = *(const half8*)(Bp + 1536);

#pragma unroll
    for (int s16 = 0; s16 < 16; ++s16) {
        const int s = kh * 16 + s16;
        float4 nsa, nsb; unsigned long long nw;
        half8 nb0, nb1, nb2, nb3;
        if (s16 < 15) {
            const int jn = (s + 1) * 32 + fq * 8;
            nsa = *(const float4*)&sjr[jn];
            nsb = *(const float4*)&sjr[jn + 4];
            nw  = arow[(s + 1) >> 1];
            const _Float16* bn = Bp + (size_t)(s16 + 1) * 2048;
            nb0 = *(const half8*)(bn);
            nb1 = *(const half8*)(bn + 512);
            nb2 = *(const half8*)(bn + 1024);
            nb3 = *(const half8*)(bn + 1536);
        }
        const int bb = (s & 1) * 32 + fq * 8;
        const float sv[8] = {sa.x, sa.y, sa.z, sa.w, sb.x, sb.y, sb.z, sb.w};
        float p[8];
        if (w == ~0ULL) {
#pragma unroll
            for (int t = 0; t < 8; ++t) {
                float e = s_i + sv[t];
                e = fmaxf(e, ALPHAc * e) - m_i;
                p[t] = __expf(e);
            }
        } else {
#pragma unroll
            for (int t = 0; t < 8; ++t) {
                float e = s_i + sv[t];
                e = fmaxf(e, ALPHAc * e) - m_i;
                e = ((w >> (bb + t)) & 1) ? e : -1e30f;
                p[t] = __expf(e);
            }
        }
        zacc += ((p[0] + p[1]) + (p[2] + p[3])) + ((p[4] + p[5]) + (p[6] + p[7]));
        union { half8 v; _Float16 h[8]; } A;
#pragma unroll
        for (int t = 0; t < 8; ++t) A.h[t] = (_Float16)p[t];
        acc[0] = __builtin_amdgcn_mfma_f32_16x16x32_f16(A.v, bfr0, acc[0], 0, 0, 0);
        acc[1] = __builtin_amdgcn_mfma_f32_16x16x32_f16(A.v, bfr1, acc[1], 0, 0, 0);
        acc[2] = __builtin_amdgcn_mfma_f32_16x16x32_f16(A.v, bfr2, acc[2], 0, 0, 0);
        acc[3] = __builtin_amdgcn_mfma_f32_16x16x32_f16(A.v, bfr3, acc[3], 0, 0, 0);
        if (s16 < 15) {
            sa = nsa; sb = nsb; w = nw;
            bfr0 = nb0; bfr1 = nb1; bfr2 = nb2; bfr3 = nb3;
        }
    }

    zacc += __shfl_xor(zacc, 16, 64);
    zacc += __shfl_xor(zacc, 32, 64);
    if (lane < 16) uR.ag.zs[wv][lane] = zacc;
#pragma unroll
    for (int c = 0; c < 4; ++c)
        *(floatx4*)&uR.ag.red[wv][lane][c * 4] = acc[c];
    __syncthreads();

    // combine K-halves; ELU; write fp16 xh tile to LDS (col = hh*64 + c*16 + fr)
    {
        const int w0 = hh * 2;
#pragma unroll
        for (int cc = 0; cc < 2; ++cc) {
            const int c = kh * 2 + cc;
#pragma unroll
            for (int reg = 0; reg < 4; ++reg) {
                const int r = fq * 4 + reg;
                const float af = uR.ag.red[w0][lane][c * 4 + reg]
                               + uR.ag.red[w0 + 1][lane][c * 4 + reg];
                const float Z = uR.ag.zs[w0][r] + uR.ag.zs[w0 + 1][r];
                float v = af / Z;
                v = v > 0.f ? v : expm1f(v);   // inter-layer ELU
                xhs[r][hh * 64 + c * 16 + fr] = (_Float16)v;
            }
        }
    }
    __syncthreads();   // xhs ready; uR.ag dead

    // ---- proj2: Wh2 = xh @ W2 for these 16 rows. Wave (hh, kh): cols
    // hh*64 + kh*32 + {0..31}. A from LDS xhs, B from W2T (L2-hot).
    floatx4 a2c0 = {0.f,0.f,0.f,0.f}, a2c1 = {0.f,0.f,0.f,0.f};
#pragma unroll
    for (int ks = 0; ks < 6; ++ks) {
        half8 af2 = *(const half8*)&xhs[fr][ks * 32 + fq * 8];
        const _Float16* wb = W2T + (size_t)((hh * 6 + ks) * 2 + kh) * 1024 + lane * 8;
        half8 b0 = *(const half8*)wb;
        half8 b1 = *(const half8*)(wb + 512);
        a2c0 = __builtin_amdgcn_mfma_f32_16x16x32_f16(af2, b0, a2c0, 0, 0, 0);
        a2c1 = __builtin_amdgcn_mfma_f32_16x16x32_f16(af2, b1, a2c1, 0, 0, 0);
    }

    // partial s_i2/s_j2 over this wave's 32 cols
    {
        const float* a2h = a2 + hh * 2 * Dc;
        const float al0 = a2h[kh * 32 + fr];
        const float al1 = a2h[kh * 32 + 16 + fr];
        const float ar0 = a2h[Dc + kh * 32 + fr];
        const float ar1 = a2h[Dc + kh * 32 + 16 + fr];
#pragma unroll
        for (int reg = 0; reg < 4; ++reg) {
            float pi = a2c0[reg] * al0 + a2c1[reg] * al1;
            float pj = a2c0[reg] * ar0 + a2c1[reg] * ar1;
            for (int off = 8; off >= 1; off >>= 1) {
                pi += __shfl_xor(pi, off, 64);
                pj += __shfl_xor(pj, off, 64);
            }
            if (fr == 0) {
                sp2i[wv][fq * 4 + reg] = pi;
                sp2j[wv][fq * 4 + reg] = pj;
            }
        }
    }
    __syncthreads();   // sp2 ready; xhs dead

    // finalize si2/sj2/Mp2 (one wave per head) + stage Wh2 into Ts3
    if (kh == 0 && lane < 16) {
        const int r = lane;
        float vi = sp2i[wv][r] + sp2i[wv + 1][r];
        float vj = sp2j[wv][r] + sp2j[wv + 1][r];
        si2[(size_t)bh * Nc + row0 + r] = vi;
        sj2[(size_t)bh * Nc + row0 + r] = vj;
        float mv = vj;
        for (int off = 8; off >= 1; off >>= 1) mv = fmaxf(mv, __shfl_xor(mv, off, 64));
        if (r == 0) Mp2[bh * 64 + c16] = mv;
    }
#pragma unroll
    for (int cc = 0; cc < 2; ++cc) {
        const int d = kh * 32 + cc * 16 + fr;
        floatx4 av = cc ? a2c1 : a2c0;
#pragma unroll
        for (int p = 0; p < 2; ++p) {
            union { unsigned int w2; _Float16 h[2]; } pk;
            pk.h[0] = (_Float16)av[2 * p];
            pk.h[1] = (_Float16)av[2 * p + 1];
            *(unsigned int*)&uR.Ts3[hh][d][fq * 4 + 2 * p] = pk.w2;
        }
    }
    __syncthreads();

    // swizzled WhT2 store: 3 heads x 64 d x 2 row-octets = 384 uint4s
    {
        const int hh3 = tid / 128, rem = tid % 128, d3 = rem >> 1, rr = rem & 1;
        uint4 v = *(const uint4*)&uR.Ts3[hh3][d3][rr * 8];
        const int bh3 = b * NHc + hh3;
        const int jt = c16 >> 1;
        const int c3 = d3 >> 4;
        const int fqp = (c16 & 1) * 2 + rr;
        *(uint4*)&WhT2[((((size_t)(bh3 * 32 + jt) * 4 + c3) * 64) + fqp * 16 + (d3 & 15)) * 8] = v;
    }
}

// ---------------------------------------------------------------------------
// P3: aggr layer 2 (R7-proven structure). Block = 4 waves, wave = K=256 slice
// of (bh, 16-row chunk); pipelined; one end-of-kernel LDS reduction.
// Grid 1536 x 256.
// ---------------------------------------------------------------------------
__global__ __launch_bounds__(256, 4) void k_aggr2(
    const _Float16* __restrict__ WhT,
    const float* __restrict__ si, const float* __restrict__ sj,
    const float* __restrict__ Mp2, const unsigned long long* __restrict__ adjb,
    float* __restrict__ out)
{
    __shared__ float red[4][64][20];
    __shared__ float zs[4][16];

    const int tid  = threadIdx.x;
    const int wv   = tid >> 6, lane = tid & 63;
    const int bh   = blockIdx.x >> 6;
    const int row0 = (blockIdx.x & 63) << 4;
    const int b    = bh / NHc, hh = bh % NHc;
    const int fr   = lane & 15, fq = lane >> 4;
    const int row  = row0 + fr;

    float mpv = Mp2[bh * 64 + lane];
    for (int off = 32; off >= 1; off >>= 1) mpv = fmaxf(mpv, __shfl_xor(mpv, off, 64));

    const float s_i = si[(size_t)bh * Nc + row];
    const float em  = s_i + mpv;
    const float m_i = fmaxf(em, ALPHAc * em);

    const float* sjr = sj + (size_t)bh * Nc + fq * 8;
    const unsigned long long* arow = adjb + (size_t)row * 16;
    const _Float16* Bp = WhT + (size_t)bh * 65536 + (size_t)wv * 8 * 2048 + lane * 8;

    floatx4 acc[4] = {{0.f,0.f,0.f,0.f},{0.f,0.f,0.f,0.f},
                      {0.f,0.f,0.f,0.f},{0.f,0.f,0.f,0.f}};
    float zacc = 0.f;

    float4 sa = *(const float4*)&sjr[wv * 256];
    float4 sb = *(const float4*)&sjr[wv * 256 + 4];
    unsigned long long w = arow[(wv * 8) >> 1];
    half8 bfr0 = *(const half8*)(Bp);
    half8 bfr1 = *(const half8*)(Bp + 512);
    half8 bfr2 = *(const half8*)(Bp + 1024);
    half8 bfr3 = *(const half8*)(Bp + 1536);

#pragma unroll
    for (int s8 = 0; s8 < 8; ++s8) {
        const int s = wv * 8 + s8;
        float4 nsa, nsb; unsigned long long nw;
        half8 nb0, nb1, nb2, nb3;
        if (s8 < 7) {
            nsa = *(const float4*)&sjr[(s + 1) * 32];
            nsb = *(const float4*)&sjr[(s + 1) * 32 + 4];
            nw  = arow[(s + 1) >> 1];
            const _Float16* bn = Bp + (size_t)(s8 + 1) * 2048;
            nb0 = *(const half8*)(bn);
            nb1 = *(const half8*)(bn + 512);
            nb2 = *(const half8*)(bn + 1024);
            nb3 = *(const half8*)(bn + 1536);
        }
        const int bb = (s & 1) * 32 + fq * 8;
        const float sv[8] = {sa.x, sa.y, sa.z, sa.w, sb.x, sb.y, sb.z, sb.w};
        float p[8];
        if (w == ~0ULL) {
#pragma unroll
            for (int t = 0; t < 8; ++t) {
                float e = s_i + sv[t];
                e = fmaxf(e, ALPHAc * e) - m_i;
                p[t] = __expf(e);
            }
        } else {
#pragma unroll
            for (int t = 0; t < 8; ++t) {
                float e = s_i + sv[t];
                e = fmaxf(e, ALPHAc * e) - m_i;
                e = ((w >> (bb + t)) & 1) ? e : -1e30f;
                p[t] = __expf(e);
            }
        }
        zacc += ((p[0] + p[1]) + (p[2] + p[3])) + ((p[4] + p[5]) + (p[6] + p[7]));
        union { half8 v; _Float16 h[8]; } A;
#pragma unroll
        for (int t = 0; t < 8; ++t) A.h[t] = (_Float16)p[t];
        acc[0] = __builtin_amdgcn_mfma_f32_16x16x32_f16(A.v, bfr0, acc[0], 0, 0, 0);
        acc[1] = __builtin_amdgcn_mfma_f32_16x16x32_f16(A.v, bfr1, acc[1], 0, 0, 0);
        acc[2] = __builtin_amdgcn_mfma_f32_16x16x32_f16(A.v, bfr2, acc[2], 0, 0, 0);
        acc[3] = __builtin_amdgcn_mfma_f32_16x16x32_f16(A.v, bfr3, acc[3], 0, 0, 0);
        if (s8 < 7) {
            sa = nsa; sb = nsb; w = nw;
            bfr0 = nb0; bfr1 = nb1; bfr2 = nb2; bfr3 = nb3;
        }
    }

    zacc += __shfl_xor(zacc, 16, 64);
    zacc += __shfl_xor(zacc, 32, 64);
    if (lane < 16) zs[wv][lane] = zacc;
#pragma unroll
    for (int c = 0; c < 4; ++c)
        *(floatx4*)&red[wv][lane][c * 4] = acc[c];
    __syncthreads();

    floatx4 af = {0.f, 0.f, 0.f, 0.f};
#pragma unroll
    for (int w2 = 0; w2 < 4; ++w2) {
        floatx4 r = *(const floatx4*)&red[w2][lane][wv * 4];
        af[0] += r[0]; af[1] += r[1]; af[2] += r[2]; af[3] += r[3];
    }
#pragma unroll
    for (int reg = 0; reg < 4; ++reg) {
        const int r = fq * 4 + reg;
        const float Z = (zs[0][r] + zs[1][r]) + (zs[2][r] + zs[3][r]);
        out[((size_t)b * Nc + row0 + r) * HIDc + hh * Dc + wv * 16 + fr] = af[reg] / Z;
    }
}

// ---------------------------------------------------------------------------
extern "C" void kernel_launch(void* const* d_in, const int* in_sizes, int n_in,
                              void* d_out, int out_size, void* d_ws, size_t ws_size,
                              hipStream_t stream) {
    const float* h_in = (const float*)d_in[0];   // (B,N,OBS)
    const float* adj  = (const float*)d_in[1];   // (N,N)
    const float* W1   = (const float*)d_in[2];   // (NH,OBS,D)
    const float* a1   = (const float*)d_in[3];   // (NH,2D)
    const float* W2   = (const float*)d_in[4];   // (NH,HID,D)
    const float* a2   = (const float*)d_in[5];   // (NH,2D)
    float* out = (float*)d_out;

    float* ws = (float*)d_ws;
    const size_t nWhT_f = (size_t)Bc * NHc * Dc * Nc / 2;   // 786432 floats each
    const size_t nAb_f  = (size_t)Nc * 16 * 2;              // 32768
    const size_t nW2T_f = 36864 / 2;                        // 18432
    const size_t nR     = (size_t)Bc * NHc * Nc;            // 24576
    _Float16* WhT1 = (_Float16*)ws;
    _Float16* WhT2 = (_Float16*)(ws + nWhT_f);
    unsigned long long* adjb = (unsigned long long*)(ws + 2 * nWhT_f);
    _Float16* W2T  = (_Float16*)(ws + 2 * nWhT_f + nAb_f);
    float* si1 = ws + 2 * nWhT_f + nAb_f + nW2T_f;
    float* sj1 = si1 + nR;
    float* si2 = sj1 + nR;
    float* sj2 = si2 + nR;
    float* Mp1 = sj2 + nR;          // 768 floats (24 bh x 32 chunks)
    float* Mp2 = Mp1 + 768;         // 1536 floats (24 bh x 64 chunks)

    // P1: proj1 + aux (adj pack, W2 swizzle)
    k_proj1<<<dim3(Nc / 32, Bc * NHc + 1), 256, 0, stream>>>(
        h_in, W1, a1, WhT1, si1, sj1, Mp1, adj, adjb, W2, W2T);

    // P2: aggr1 + ELU + proj2 fused (xh tile lives only in LDS)
    k_fused<<<512, 384, 0, stream>>>(
        WhT1, si1, sj1, Mp1, adjb, W2T, a2, WhT2, si2, sj2, Mp2);

    // P3: aggr2 -> out
    k_aggr2<<<1536, 256, 0, stream>>>(WhT2, si2, sj2, Mp2, adjb, out);
}

// Round 11
// 117.635 us; speedup vs baseline: 3.4591x; 1.0132x over previous
//
#include <hip/hip_runtime.h>
#include <math.h>

// Problem constants (GNNObservationEncoder: 2-layer GAT, full graph)
#define Bc   8
#define Nc   1024
#define OBSc 64
#define HIDc 192
#define NHc  3
#define Dc   64
#define ALPHAc 0.2f

typedef __attribute__((ext_vector_type(8))) _Float16 half8;
typedef __attribute__((ext_vector_type(4))) float floatx4;

// WhT swizzled (MFMA B-fragment order):
//   idx(bh, jt, c, lane, t) = (((bh*32 + jt)*4 + c)*64 + lane)*8 + t
//   element = Wh[j = jt*32 + (lane>>4)*8 + t][d = c*16 + (lane&15)]

// ---------------------------------------------------------------------------
// P1: proj1 (Wh1 = x @ W1, fp16 MFMA) + aux y-slice (adj bit-pack, W2->W2T).
// ---------------------------------------------------------------------------
__global__ __launch_bounds__(256) void k_proj1(
    const float* __restrict__ xin, const float* __restrict__ W1,
    const float* __restrict__ a1, _Float16* __restrict__ WhT,
    float* __restrict__ si, float* __restrict__ sj, float* __restrict__ Mp1,
    const float* __restrict__ adj, unsigned long long* __restrict__ adjb,
    const float* __restrict__ W2, _Float16* __restrict__ W2T)
{
    const int tid = threadIdx.x;
    const int bh  = blockIdx.y;

    if (bh == Bc * NHc) {
        const int px = blockIdx.x, wv = tid >> 6, lane = tid & 63;
        for (int r8 = 0; r8 < 8; ++r8) {
            const int i = px * 32 + wv * 8 + r8;
            unsigned long long word = 0;
            for (int g = 0; g < 16; ++g) {
                bool c = adj[(size_t)i * Nc + g * 64 + lane] > 0.f;
                unsigned long long bal = __ballot(c);
                if (lane == g) word = bal;
            }
            if (lane < 16) adjb[(size_t)i * 16 + lane] = word;
        }
        if (px < 12) {
            for (int e = px * 3072 + tid; e < px * 3072 + 3072; e += 256) {
                int t = e & 7, ln = (e >> 3) & 63, p = (e >> 9) & 1, nh = (e >> 10) & 1;
                int g = e >> 11; int ks = g % 6, hh = g / 6;
                int k = ks * 32 + (ln >> 4) * 8 + t;
                int d = nh * 32 + p * 16 + (ln & 15);
                W2T[e] = (_Float16)W2[((size_t)hh * HIDc + k) * Dc + d];
            }
        }
        return;
    }

    __shared__ union {
        _Float16 Bs[64][OBSc + 8];
        _Float16 Ts[64][40];
    } u;
    __shared__ float spsAi[32], spsAj[32], spsBi[32], spsBj[32];

    const int b = bh / NHc, hh = bh % NHc;
    const int row0 = blockIdx.x * 32;

    for (int e = tid; e < OBSc * 64; e += 256) {
        int k = e >> 6, d = e & 63;
        u.Bs[d][k] = (_Float16)W1[(size_t)hh * OBSc * 64 + e];
    }
    __syncthreads();

    const int lane = tid & 63, wv = tid >> 6;
    const int mblk = (wv & 1) * 16, nhalf = (wv >> 1) * 32;
    const int fr = lane & 15, fq = lane >> 4;
    floatx4 acc0 = {0.f,0.f,0.f,0.f}, acc1 = {0.f,0.f,0.f,0.f};
    const int row = row0 + mblk + fr;

#pragma unroll
    for (int ks = 0; ks < OBSc / 32; ++ks) {
        const int k0 = ks * 32 + fq * 8;
        const float* xr = xin + ((size_t)b * Nc + row) * OBSc + k0;
        float4 u0 = *(const float4*)xr;
        float4 u1 = *(const float4*)(xr + 4);
        half8 af;
        af[0] = (_Float16)u0.x; af[1] = (_Float16)u0.y;
        af[2] = (_Float16)u0.z; af[3] = (_Float16)u0.w;
        af[4] = (_Float16)u1.x; af[5] = (_Float16)u1.y;
        af[6] = (_Float16)u1.z; af[7] = (_Float16)u1.w;
        half8 b0 = *(const half8*)&u.Bs[nhalf + fr][k0];
        half8 b1 = *(const half8*)&u.Bs[nhalf + 16 + fr][k0];
        acc0 = __builtin_amdgcn_mfma_f32_16x16x32_f16(af, b0, acc0, 0, 0, 0);
        acc1 = __builtin_amdgcn_mfma_f32_16x16x32_f16(af, b1, acc1, 0, 0, 0);
    }

    const float al0 = a1[hh * 2 * Dc + nhalf + fr];
    const float al1 = a1[hh * 2 * Dc + nhalf + 16 + fr];
    const float ar0 = a1[hh * 2 * Dc + Dc + nhalf + fr];
    const float ar1 = a1[hh * 2 * Dc + Dc + nhalf + 16 + fr];
    float pi[4], pj[4];
#pragma unroll
    for (int r = 0; r < 4; ++r) {
        pi[r] = acc0[r] * al0 + acc1[r] * al1;
        pj[r] = acc0[r] * ar0 + acc1[r] * ar1;
        for (int off = 8; off >= 1; off >>= 1) {
            pi[r] += __shfl_xor(pi[r], off, 64);
            pj[r] += __shfl_xor(pj[r], off, 64);
        }
    }
    if (fr == 0) {
#pragma unroll
        for (int r = 0; r < 4; ++r) {
            int lr = mblk + fq * 4 + r;
            if (nhalf == 0) { spsAi[lr] = pi[r]; spsAj[lr] = pj[r]; }
            else            { spsBi[lr] = pi[r]; spsBj[lr] = pj[r]; }
        }
    }
    __syncthreads();
    if (tid < 64) {
        float vj = -INFINITY;
        if (tid < 32) {
            size_t g = (size_t)bh * Nc + row0 + tid;
            si[g] = spsAi[tid] + spsBi[tid];
            vj    = spsAj[tid] + spsBj[tid];
            sj[g] = vj;
        }
        float mv = vj;
        for (int off = 32; off >= 1; off >>= 1) mv = fmaxf(mv, __shfl_xor(mv, off, 64));
        if (tid == 0) Mp1[bh * 32 + blockIdx.x] = mv;
    }

#pragma unroll
    for (int nt = 0; nt < 2; ++nt) {
        const int d = nhalf + nt * 16 + fr;
        floatx4 acc = nt ? acc1 : acc0;
#pragma unroll
        for (int p = 0; p < 2; ++p) {
            union { unsigned int w; _Float16 h[2]; } pk;
            pk.h[0] = (_Float16)acc[2 * p];
            pk.h[1] = (_Float16)acc[2 * p + 1];
            *(unsigned int*)&u.Ts[d][mblk + fq * 4 + 2 * p] = pk.w;
        }
    }
    __syncthreads();
    {
        const int c2 = tid >> 6, lane2 = tid & 63;
        const int fr2 = lane2 & 15, fq2 = lane2 >> 4;
        const int jt = row0 >> 5;
        uint4 v = *(const uint4*)&u.Ts[c2 * 16 + fr2][fq2 * 8];
        *(uint4*)&WhT[(size_t)(bh * 32 + jt) * 2048 + tid * 8] = v;
    }
}

// ---------------------------------------------------------------------------
// P2: aggr1 + ELU + proj2 fused. Block = (b, 16-row chunk), 384 thr.
// R11: sj/adjb preloaded to LDS (K-loop in-flight set = B-frags only);
// 3-deep B-fragment prefetch. (384,2): VGPR cap 170.
// ---------------------------------------------------------------------------
__global__ __launch_bounds__(384, 2) void k_fused(
    const _Float16* __restrict__ WhT1,
    const float* __restrict__ si1, const float* __restrict__ sj1,
    const float* __restrict__ Mp1, const unsigned long long* __restrict__ adjb,
    const _Float16* __restrict__ W2T, const float* __restrict__ a2,
    _Float16* __restrict__ WhT2,
    float* __restrict__ si2, float* __restrict__ sj2, float* __restrict__ Mp2)
{
    __shared__ union {
        struct { float red[6][64][20]; float zs[6][16]; } ag;  // ~31.1 KB
        _Float16 Ts3[3][64][24];
    } uR;
    __shared__ _Float16 xhs[16][208];
    __shared__ float sp2i[6][16], sp2j[6][16];
    __shared__ float sjs[3][1024];                  // 12 KB
    __shared__ unsigned long long adjs[16][16];     // 2 KB

    const int tid = threadIdx.x, wv = tid >> 6, lane = tid & 63;
    const int b = blockIdx.x >> 6, c16 = blockIdx.x & 63;
    const int row0 = c16 * 16;
    const int hh = wv >> 1, kh = wv & 1;
    const int bh = b * NHc + hh;
    const int fr = lane & 15, fq = lane >> 4;
    const int row = row0 + fr;

    // ---- preload sj (3 heads) + adjb (16 rows) into LDS
    for (int e = tid; e < 768; e += 384) {       // 768 float4s
        int h = e >> 8, idx = (e & 255) * 4;
        *(float4*)&sjs[h][idx] = *(const float4*)&sj1[(size_t)(b * NHc + h) * Nc + idx];
    }
    if (tid < 256)
        adjs[tid >> 4][tid & 15] = adjb[(size_t)(row0 + (tid >> 4)) * 16 + (tid & 15)];
    __syncthreads();

    // ---- aggr layer 1 (K-half kh) ----
    float mpv = Mp1[bh * 32 + (lane & 31)];
    for (int off = 16; off >= 1; off >>= 1) mpv = fmaxf(mpv, __shfl_xor(mpv, off, 64));
    const float s_i = si1[(size_t)bh * Nc + row];
    const float em  = s_i + mpv;
    const float m_i = fmaxf(em, ALPHAc * em);

    const _Float16* Bp = WhT1 + (size_t)bh * 65536 + (size_t)kh * 32768 + lane * 8;

    floatx4 acc[4] = {{0.f,0.f,0.f,0.f},{0.f,0.f,0.f,0.f},
                      {0.f,0.f,0.f,0.f},{0.f,0.f,0.f,0.f}};
    float zacc = 0.f;

    // 3-deep B pipeline
    half8 bf[3][4];
#pragma unroll
    for (int st = 0; st < 2; ++st)
#pragma unroll
        for (int c = 0; c < 4; ++c)
            bf[st][c] = *(const half8*)(Bp + (size_t)st * 2048 + c * 512);

#pragma unroll
    for (int s16 = 0; s16 < 16; ++s16) {
        const int s   = kh * 16 + s16;
        const int cur = s16 % 3;
        if (s16 < 14) {
            const int nxt = (s16 + 2) % 3;
            const _Float16* bn = Bp + (size_t)(s16 + 2) * 2048;
#pragma unroll
            for (int c = 0; c < 4; ++c)
                bf[nxt][c] = *(const half8*)(bn + c * 512);
        }
        const float4 sa = *(const float4*)&sjs[hh][s * 32 + fq * 8];
        const float4 sb = *(const float4*)&sjs[hh][s * 32 + fq * 8 + 4];
        const unsigned long long w = adjs[fr][s >> 1];
        const int bb = (s & 1) * 32 + fq * 8;
        const float sv[8] = {sa.x, sa.y, sa.z, sa.w, sb.x, sb.y, sb.z, sb.w};
        float p[8];
        if (w == ~0ULL) {
#pragma unroll
            for (int t = 0; t < 8; ++t) {
                float e = s_i + sv[t];
                e = fmaxf(e, ALPHAc * e) - m_i;
                p[t] = __expf(e);
            }
        } else {
#pragma unroll
            for (int t = 0; t < 8; ++t) {
                float e = s_i + sv[t];
                e = fmaxf(e, ALPHAc * e) - m_i;
                e = ((w >> (bb + t)) & 1) ? e : -1e30f;
                p[t] = __expf(e);
            }
        }
        zacc += ((p[0] + p[1]) + (p[2] + p[3])) + ((p[4] + p[5]) + (p[6] + p[7]));
        union { half8 v; _Float16 h[8]; } A;
#pragma unroll
        for (int t = 0; t < 8; ++t) A.h[t] = (_Float16)p[t];
        acc[0] = __builtin_amdgcn_mfma_f32_16x16x32_f16(A.v, bf[cur][0], acc[0], 0, 0, 0);
        acc[1] = __builtin_amdgcn_mfma_f32_16x16x32_f16(A.v, bf[cur][1], acc[1], 0, 0, 0);
        acc[2] = __builtin_amdgcn_mfma_f32_16x16x32_f16(A.v, bf[cur][2], acc[2], 0, 0, 0);
        acc[3] = __builtin_amdgcn_mfma_f32_16x16x32_f16(A.v, bf[cur][3], acc[3], 0, 0, 0);
    }

    zacc += __shfl_xor(zacc, 16, 64);
    zacc += __shfl_xor(zacc, 32, 64);
    if (lane < 16) uR.ag.zs[wv][lane] = zacc;
#pragma unroll
    for (int c = 0; c < 4; ++c)
        *(floatx4*)&uR.ag.red[wv][lane][c * 4] = acc[c];
    __syncthreads();

    // combine K-halves; ELU; fp16 xh tile in LDS
    {
        const int w0 = hh * 2;
#pragma unroll
        for (int cc = 0; cc < 2; ++cc) {
            const int c = kh * 2 + cc;
#pragma unroll
            for (int reg = 0; reg < 4; ++reg) {
                const int r = fq * 4 + reg;
                const float af = uR.ag.red[w0][lane][c * 4 + reg]
                               + uR.ag.red[w0 + 1][lane][c * 4 + reg];
                const float Z = uR.ag.zs[w0][r] + uR.ag.zs[w0 + 1][r];
                float v = af / Z;
                v = v > 0.f ? v : expm1f(v);
                xhs[r][hh * 64 + c * 16 + fr] = (_Float16)v;
            }
        }
    }
    __syncthreads();

    // ---- proj2 from LDS xh tile + W2T
    floatx4 a2c0 = {0.f,0.f,0.f,0.f}, a2c1 = {0.f,0.f,0.f,0.f};
#pragma unroll
    for (int ks = 0; ks < 6; ++ks) {
        half8 af2 = *(const half8*)&xhs[fr][ks * 32 + fq * 8];
        const _Float16* wb = W2T + (size_t)((hh * 6 + ks) * 2 + kh) * 1024 + lane * 8;
        half8 b0 = *(const half8*)wb;
        half8 b1 = *(const half8*)(wb + 512);
        a2c0 = __builtin_amdgcn_mfma_f32_16x16x32_f16(af2, b0, a2c0, 0, 0, 0);
        a2c1 = __builtin_amdgcn_mfma_f32_16x16x32_f16(af2, b1, a2c1, 0, 0, 0);
    }

    {
        const float* a2h = a2 + hh * 2 * Dc;
        const float al0 = a2h[kh * 32 + fr];
        const float al1 = a2h[kh * 32 + 16 + fr];
        const float ar0 = a2h[Dc + kh * 32 + fr];
        const float ar1 = a2h[Dc + kh * 32 + 16 + fr];
#pragma unroll
        for (int reg = 0; reg < 4; ++reg) {
            float pi = a2c0[reg] * al0 + a2c1[reg] * al1;
            float pj = a2c0[reg] * ar0 + a2c1[reg] * ar1;
            for (int off = 8; off >= 1; off >>= 1) {
                pi += __shfl_xor(pi, off, 64);
                pj += __shfl_xor(pj, off, 64);
            }
            if (fr == 0) {
                sp2i[wv][fq * 4 + reg] = pi;
                sp2j[wv][fq * 4 + reg] = pj;
            }
        }
    }
    __syncthreads();

    if (kh == 0 && lane < 16) {
        const int r = lane;
        float vi = sp2i[wv][r] + sp2i[wv + 1][r];
        float vj = sp2j[wv][r] + sp2j[wv + 1][r];
        si2[(size_t)bh * Nc + row0 + r] = vi;
        sj2[(size_t)bh * Nc + row0 + r] = vj;
        float mv = vj;
        for (int off = 8; off >= 1; off >>= 1) mv = fmaxf(mv, __shfl_xor(mv, off, 64));
        if (r == 0) Mp2[bh * 64 + c16] = mv;
    }
#pragma unroll
    for (int cc = 0; cc < 2; ++cc) {
        const int d = kh * 32 + cc * 16 + fr;
        floatx4 av = cc ? a2c1 : a2c0;
#pragma unroll
        for (int p = 0; p < 2; ++p) {
            union { unsigned int w2; _Float16 h[2]; } pk;
            pk.h[0] = (_Float16)av[2 * p];
            pk.h[1] = (_Float16)av[2 * p + 1];
            *(unsigned int*)&uR.Ts3[hh][d][fq * 4 + 2 * p] = pk.w2;
        }
    }
    __syncthreads();

    {
        const int hh3 = tid / 128, rem = tid % 128, d3 = rem >> 1, rr = rem & 1;
        uint4 v = *(const uint4*)&uR.Ts3[hh3][d3][rr * 8];
        const int bh3 = b * NHc + hh3;
        const int jt = c16 >> 1;
        const int c3 = d3 >> 4;
        const int fqp = (c16 & 1) * 2 + rr;
        *(uint4*)&WhT2[((((size_t)(bh3 * 32 + jt) * 4 + c3) * 64) + fqp * 16 + (d3 & 15)) * 8] = v;
    }
}

// ---------------------------------------------------------------------------
// P3: aggr layer 2. R11: sj/adjb LDS preload + 3-deep B prefetch.
// Block = 4 waves, wave = K=256 slice of (bh, 16-row chunk). Grid 1536 x 256.
// ---------------------------------------------------------------------------
__global__ __launch_bounds__(256, 4) void k_aggr2(
    const _Float16* __restrict__ WhT,
    const float* __restrict__ si, const float* __restrict__ sj,
    const float* __restrict__ Mp2, const unsigned long long* __restrict__ adjb,
    float* __restrict__ out)
{
    __shared__ float red[4][64][20];
    __shared__ float zs[4][16];
    __shared__ float sjs[1024];                    // 4 KB
    __shared__ unsigned long long adjs[16][16];    // 2 KB

    const int tid  = threadIdx.x;
    const int wv   = tid >> 6, lane = tid & 63;
    const int bh   = blockIdx.x >> 6;
    const int row0 = (blockIdx.x & 63) << 4;
    const int b    = bh / NHc, hh = bh % NHc;
    const int fr   = lane & 15, fq = lane >> 4;
    const int row  = row0 + fr;

    for (int e = tid; e < 256; e += 256)
        *(float4*)&sjs[e * 4] = *(const float4*)&sj[(size_t)bh * Nc + e * 4];
    if (tid < 256 && tid >= 0) { /* all threads */ }
    if (tid < 256)
        adjs[tid >> 4][tid & 15] = adjb[(size_t)(row0 + (tid >> 4)) * 16 + (tid & 15)];
    __syncthreads();

    float mpv = Mp2[bh * 64 + lane];
    for (int off = 32; off >= 1; off >>= 1) mpv = fmaxf(mpv, __shfl_xor(mpv, off, 64));

    const float s_i = si[(size_t)bh * Nc + row];
    const float em  = s_i + mpv;
    const float m_i = fmaxf(em, ALPHAc * em);

    const _Float16* Bp = WhT + (size_t)bh * 65536 + (size_t)wv * 8 * 2048 + lane * 8;

    floatx4 acc[4] = {{0.f,0.f,0.f,0.f},{0.f,0.f,0.f,0.f},
                      {0.f,0.f,0.f,0.f},{0.f,0.f,0.f,0.f}};
    float zacc = 0.f;

    half8 bf[3][4];
#pragma unroll
    for (int st = 0; st < 2; ++st)
#pragma unroll
        for (int c = 0; c < 4; ++c)
            bf[st][c] = *(const half8*)(Bp + (size_t)st * 2048 + c * 512);

#pragma unroll
    for (int s8 = 0; s8 < 8; ++s8) {
        const int s   = wv * 8 + s8;
        const int cur = s8 % 3;
        if (s8 < 6) {
            const int nxt = (s8 + 2) % 3;
            const _Float16* bn = Bp + (size_t)(s8 + 2) * 2048;
#pragma unroll
            for (int c = 0; c < 4; ++c)
                bf[nxt][c] = *(const half8*)(bn + c * 512);
        }
        const float4 sa = *(const float4*)&sjs[s * 32 + fq * 8];
        const float4 sb = *(const float4*)&sjs[s * 32 + fq * 8 + 4];
        const unsigned long long w = adjs[fr][s >> 1];
        const int bb = (s & 1) * 32 + fq * 8;
        const float sv[8] = {sa.x, sa.y, sa.z, sa.w, sb.x, sb.y, sb.z, sb.w};
        float p[8];
        if (w == ~0ULL) {
#pragma unroll
            for (int t = 0; t < 8; ++t) {
                float e = s_i + sv[t];
                e = fmaxf(e, ALPHAc * e) - m_i;
                p[t] = __expf(e);
            }
        } else {
#pragma unroll
            for (int t = 0; t < 8; ++t) {
                float e = s_i + sv[t];
                e = fmaxf(e, ALPHAc * e) - m_i;
                e = ((w >> (bb + t)) & 1) ? e : -1e30f;
                p[t] = __expf(e);
            }
        }
        zacc += ((p[0] + p[1]) + (p[2] + p[3])) + ((p[4] + p[5]) + (p[6] + p[7]));
        union { half8 v; _Float16 h[8]; } A;
#pragma unroll
        for (int t = 0; t < 8; ++t) A.h[t] = (_Float16)p[t];
        acc[0] = __builtin_amdgcn_mfma_f32_16x16x32_f16(A.v, bf[cur][0], acc[0], 0, 0, 0);
        acc[1] = __builtin_amdgcn_mfma_f32_16x16x32_f16(A.v, bf[cur][1], acc[1], 0, 0, 0);
        acc[2] = __builtin_amdgcn_mfma_f32_16x16x32_f16(A.v, bf[cur][2], acc[2], 0, 0, 0);
        acc[3] = __builtin_amdgcn_mfma_f32_16x16x32_f16(A.v, bf[cur][3], acc[3], 0, 0, 0);
    }

    zacc += __shfl_xor(zacc, 16, 64);
    zacc += __shfl_xor(zacc, 32, 64);
    if (lane < 16) zs[wv][lane] = zacc;
#pragma unroll
    for (int c = 0; c < 4; ++c)
        *(floatx4*)&red[wv][lane][c * 4] = acc[c];
    __syncthreads();

    floatx4 af = {0.f, 0.f, 0.f, 0.f};
#pragma unroll
    for (int w2 = 0; w2 < 4; ++w2) {
        floatx4 r = *(const floatx4*)&red[w2][lane][wv * 4];
        af[0] += r[0]; af[1] += r[1]; af[2] += r[2]; af[3] += r[3];
    }
#pragma unroll
    for (int reg = 0; reg < 4; ++reg) {
        const int r = fq * 4 + reg;
        const float Z = (zs[0][r] + zs[1][r]) + (zs[2][r] + zs[3][r]);
        out[((size_t)b * Nc + row0 + r) * HIDc + hh * Dc + wv * 16 + fr] = af[reg] / Z;
    }
}

// ---------------------------------------------------------------------------
extern "C" void kernel_launch(void* const* d_in, const int* in_sizes, int n_in,
                              void* d_out, int out_size, void* d_ws, size_t ws_size,
                              hipStream_t stream) {
    const float* h_in = (const float*)d_in[0];
    const float* adj  = (const float*)d_in[1];
    const float* W1   = (const float*)d_in[2];
    const float* a1   = (const float*)d_in[3];
    const float* W2   = (const float*)d_in[4];
    const float* a2   = (const float*)d_in[5];
    float* out = (float*)d_out;

    float* ws = (float*)d_ws;
    const size_t nWhT_f = (size_t)Bc * NHc * Dc * Nc / 2;
    const size_t nAb_f  = (size_t)Nc * 16 * 2;
    const size_t nW2T_f = 36864 / 2;
    const size_t nR     = (size_t)Bc * NHc * Nc;
    _Float16* WhT1 = (_Float16*)ws;
    _Float16* WhT2 = (_Float16*)(ws + nWhT_f);
    unsigned long long* adjb = (unsigned long long*)(ws + 2 * nWhT_f);
    _Float16* W2T  = (_Float16*)(ws + 2 * nWhT_f + nAb_f);
    float* si1 = ws + 2 * nWhT_f + nAb_f + nW2T_f;
    float* sj1 = si1 + nR;
    float* si2 = sj1 + nR;
    float* sj2 = si2 + nR;
    float* Mp1 = sj2 + nR;
    float* Mp2 = Mp1 + 768;

    k_proj1<<<dim3(Nc / 32, Bc * NHc + 1), 256, 0, stream>>>(
        h_in, W1, a1, WhT1, si1, sj1, Mp1, adj, adjb, W2, W2T);

    k_fused<<<512, 384, 0, stream>>>(
        WhT1, si1, sj1, Mp1, adjb, W2T, a2, WhT2, si2, sj2, Mp2);

    k_aggr2<<<1536, 256, 0, stream>>>(WhT2, si2, sj2, Mp2, adjb, out);
}